// Round 6
// baseline (661.530 us; speedup 1.0000x reference)
//
#include <hip/hip_runtime.h>
#include <cstddef>
#include <cstdint>

#define B_    2
#define S_    2048
#define DIN_  1024
#define H_    16
#define DK_   1024
#define DV_   1024
#define DH_   64
#define DOUT_ 1024
#define M_    (B_ * S_)

typedef __attribute__((ext_vector_type(8)))  short short8;
typedef __attribute__((ext_vector_type(4)))  float float4v;
typedef __attribute__((ext_vector_type(16))) float float16v;
typedef _Float16 half8v __attribute__((ext_vector_type(8)));

__device__ __forceinline__ float bf16s_to_f(short s) {
  union { unsigned int u; float f; } cv;
  cv.u = ((unsigned int)(unsigned short)s) << 16;
  return cv.f;
}
__device__ __forceinline__ short f_to_bf16s(float f) {
  union { float f; unsigned int u; } cv;
  cv.f = f;
  unsigned int u = cv.u + 0x7FFFu + ((cv.u >> 16) & 1u);
  return (short)(u >> 16);
}
__device__ __forceinline__ short f_to_f16s(float f) {
  union { _Float16 h; short s; } cv;
  cv.h = (_Float16)f;
  return cv.s;
}
// packed f32x2 -> f16x2 (v_cvt_pkrtz_f16_f32), returned as a raw 32-bit word
__device__ __forceinline__ unsigned pkrtz_u32(float a, float b) {
  union { __fp16 __attribute__((ext_vector_type(2))) h2; unsigned u; } cv;
  cv.h2 = __builtin_amdgcn_cvt_pkrtz(a, b);   // [0]=a, [1]=b
  return cv.u;
}
__device__ __forceinline__ void gll16(const void* g, void* l) {
  __builtin_amdgcn_global_load_lds(
      (const __attribute__((address_space(1))) unsigned int*)g,
      (__attribute__((address_space(3))) unsigned int*)l, 16, 0, 0);
}

// ---------------- cast f32 -> bf16 (4 elems/thread) ----------------
__global__ __launch_bounds__(256) void cast_kernel(const float* __restrict__ in,
                                                   short* __restrict__ out, int n4) {
  int i = blockIdx.x * 256 + threadIdx.x;
  if (i >= n4) return;
  float4 v = ((const float4*)in)[i];
  union { ushort4 u; short s[4]; } o;
  o.s[0] = f_to_bf16s(v.x); o.s[1] = f_to_bf16s(v.y);
  o.s[2] = f_to_bf16s(v.z); o.s[3] = f_to_bf16s(v.w);
  ((ushort4*)out)[i] = o.u;
}

// ---------------- content bias: CBs[b,h,s] = SC*dot(x[b,s,:],Wcb[h,:]) ----
__global__ __launch_bounds__(256) void cb_kernel(const float* __restrict__ x,
                                                 const float* __restrict__ Wcb,
                                                 float* __restrict__ CBs) {
  __shared__ float xs[DIN_];
  const int row = blockIdx.x;  // b*S + s
  const int tid = threadIdx.x;
  #pragma unroll
  for (int it = 0; it < 4; ++it)
    xs[tid + it * 256] = x[(size_t)row * DIN_ + tid + it * 256];
  __syncthreads();
  const int lane = tid & 63, w = tid >> 6;
  const float SC = 0.125f * 1.44269504088896f;
  #pragma unroll
  for (int hh = 0; hh < 4; ++hh) {
    const int hidx = w * 4 + hh;
    float p = 0.f;
    for (int c = lane; c < DIN_; c += 64)
      p += xs[c] * Wcb[(size_t)hidx * DIN_ + c];
    #pragma unroll
    for (int mk = 1; mk < 64; mk <<= 1) p += __shfl_xor(p, mk);
    if (lane == 0) {
      const int bb = row / S_, ss = row % S_;
      CBs[((size_t)bb * H_ + hidx) * S_ + ss] = p * SC;
    }
  }
}

// ---------------- fused QKV projection GEMM (bf16 MFMA, f16 out) ----------
// grid (48, M/64): blockIdx.x>>4 selects Q/K/V; V is stored transposed + bias.
__global__ __launch_bounds__(256, 2) void gemm_qkv(
    const short* __restrict__ A, const short* __restrict__ Wqb,
    const short* __restrict__ Wkb, const short* __restrict__ Wvb,
    const float* __restrict__ bv, short* __restrict__ Qf,
    short* __restrict__ Kf, short* __restrict__ Vtf) {
  const int KD = 1024;
  __shared__ short As[64][136];
  __shared__ short Bs[64][136];
  const int tid  = threadIdx.x;
  const int lane = tid & 63;
  const int w    = tid >> 6;
  const int quad = lane >> 4;
  const int l16  = lane & 15;
  const int sel  = blockIdx.x >> 4;
  const int n0   = (blockIdx.x & 15) * 64;
  const int m0   = blockIdx.y * 64;
  const short* Bw = sel == 0 ? Wqb : (sel == 1 ? Wkb : Wvb);
  const int wm   = (w >> 1) * 32;
  const int wn   = (w & 1) * 32;
  const int srow = tid >> 2;
  const int sseg = (tid & 3) * 32;

  const float4v zero = {0.f, 0.f, 0.f, 0.f};
  float4v acc[2][2];
  acc[0][0] = zero; acc[0][1] = zero; acc[1][0] = zero; acc[1][1] = zero;

  for (int k0 = 0; k0 < KD; k0 += 128) {
    short8 ar[4], br[4];
    #pragma unroll
    for (int c = 0; c < 4; ++c) {
      ar[c] = *(const short8*)(A  + (size_t)(m0 + srow) * KD + k0 + sseg + c * 8);
      br[c] = *(const short8*)(Bw + (size_t)(n0 + srow) * KD + k0 + sseg + c * 8);
    }
    __syncthreads();
    #pragma unroll
    for (int c = 0; c < 4; ++c) {
      *(short8*)&As[srow][sseg + c * 8] = ar[c];
      *(short8*)&Bs[srow][sseg + c * 8] = br[c];
    }
    __syncthreads();
    #pragma unroll
    for (int ks = 0; ks < 4; ++ks) {
      short8 af0 = *(short8*)&As[wm + l16][ks * 32 + quad * 8];
      short8 af1 = *(short8*)&As[wm + 16 + l16][ks * 32 + quad * 8];
      short8 bg0 = *(short8*)&Bs[wn + l16][ks * 32 + quad * 8];
      short8 bg1 = *(short8*)&Bs[wn + 16 + l16][ks * 32 + quad * 8];
      acc[0][0] = __builtin_amdgcn_mfma_f32_16x16x32_bf16(af0, bg0, acc[0][0], 0, 0, 0);
      acc[0][1] = __builtin_amdgcn_mfma_f32_16x16x32_bf16(af0, bg1, acc[0][1], 0, 0, 0);
      acc[1][0] = __builtin_amdgcn_mfma_f32_16x16x32_bf16(af1, bg0, acc[1][0], 0, 0, 0);
      acc[1][1] = __builtin_amdgcn_mfma_f32_16x16x32_bf16(af1, bg1, acc[1][1], 0, 0, 0);
    }
  }

  #pragma unroll
  for (int mt = 0; mt < 2; ++mt)
    #pragma unroll
    for (int nt = 0; nt < 2; ++nt)
      #pragma unroll
      for (int r = 0; r < 4; ++r) {
        int row = m0 + wm + mt * 16 + quad * 4 + r;
        int col = n0 + wn + nt * 16 + l16;
        float v = acc[mt][nt][r];
        if (sel == 2) {
          v += bv[col];
          int bb = row >> 11, ss = row & 2047;
          Vtf[((size_t)bb * DV_ + col) * S_ + ss] = f_to_f16s(v);
        } else {
          short* o = sel == 0 ? Qf : Kf;
          o[(size_t)row * 1024 + col] = f_to_f16s(v);
        }
      }
}

// ---------------- out-proj GEMM: out = ctx*Wd^T + bd + resid (f32) ------
__global__ __launch_bounds__(256, 2) void gemm_out(
    const short* __restrict__ A, const short* __restrict__ Bw,
    const float* __restrict__ bias, const float* __restrict__ resid,
    float* __restrict__ outf) {
  const int KD = 1024, ND = 1024;
  __shared__ short As[64][136];
  __shared__ short Bs[64][136];
  const int tid  = threadIdx.x;
  const int lane = tid & 63;
  const int w    = tid >> 6;
  const int quad = lane >> 4;
  const int l16  = lane & 15;
  const int m0   = blockIdx.y * 64;
  const int n0   = blockIdx.x * 64;
  const int wm   = (w >> 1) * 32;
  const int wn   = (w & 1) * 32;
  const int srow = tid >> 2;
  const int sseg = (tid & 3) * 32;

  const float4v zero = {0.f, 0.f, 0.f, 0.f};
  float4v acc[2][2];
  acc[0][0] = zero; acc[0][1] = zero; acc[1][0] = zero; acc[1][1] = zero;

  for (int k0 = 0; k0 < KD; k0 += 128) {
    short8 ar[4], br[4];
    #pragma unroll
    for (int c = 0; c < 4; ++c) {
      ar[c] = *(const short8*)(A  + (size_t)(m0 + srow) * KD + k0 + sseg + c * 8);
      br[c] = *(const short8*)(Bw + (size_t)(n0 + srow) * KD + k0 + sseg + c * 8);
    }
    __syncthreads();
    #pragma unroll
    for (int c = 0; c < 4; ++c) {
      *(short8*)&As[srow][sseg + c * 8] = ar[c];
      *(short8*)&Bs[srow][sseg + c * 8] = br[c];
    }
    __syncthreads();
    #pragma unroll
    for (int ks = 0; ks < 4; ++ks) {
      short8 af0 = *(short8*)&As[wm + l16][ks * 32 + quad * 8];
      short8 af1 = *(short8*)&As[wm + 16 + l16][ks * 32 + quad * 8];
      short8 bg0 = *(short8*)&Bs[wn + l16][ks * 32 + quad * 8];
      short8 bg1 = *(short8*)&Bs[wn + 16 + l16][ks * 32 + quad * 8];
      acc[0][0] = __builtin_amdgcn_mfma_f32_16x16x32_bf16(af0, bg0, acc[0][0], 0, 0, 0);
      acc[0][1] = __builtin_amdgcn_mfma_f32_16x16x32_bf16(af0, bg1, acc[0][1], 0, 0, 0);
      acc[1][0] = __builtin_amdgcn_mfma_f32_16x16x32_bf16(af1, bg0, acc[1][0], 0, 0, 0);
      acc[1][1] = __builtin_amdgcn_mfma_f32_16x16x32_bf16(af1, bg1, acc[1][1], 0, 0, 0);
    }
  }

  #pragma unroll
  for (int mt = 0; mt < 2; ++mt)
    #pragma unroll
    for (int nt = 0; nt < 2; ++nt)
      #pragma unroll
      for (int r = 0; r < 4; ++r) {
        int row = m0 + wm + mt * 16 + quad * 4 + r;
        int col = n0 + wn + nt * 16 + l16;
        outf[(size_t)row * ND + col] =
            acc[mt][nt][r] + bias[col] + resid[(size_t)row * ND + col];
      }
}

// ---------------- fused collaborative attention v5 (pipelined DMA) --------
// 128 queries x 1 head per block, 4 waves. S^T via 32x32x16 f16 MFMA.
// K double-buffered in 64-col chunks; chunk c+1's global_load_lds issued
// right after the barrier publishing chunk c, so the next barrier's vmcnt(0)
// drain is pre-elapsed (latency hidden behind 16 MFMAs). Q register-prefetch
// one chunk ahead. XOR-swizzled K layout (phys16 = logical16 ^ (row&7)).
__global__ __launch_bounds__(256, 2) void attn_kernel(
    const short* __restrict__ Qf, const short* __restrict__ Kf,
    const short* __restrict__ Vtf, const float* __restrict__ mixing,
    const float* __restrict__ CBs, short* __restrict__ ctxb) {
  __shared__ __align__(16) short Kbuf[2][128 * 64];  // 2 x 16 KB
  __shared__ __align__(16) short Vt[64][136];        // V^T tile [dv][j], f16
  __shared__ __align__(16) short mix_s[DK_];         // f16(mix*SC)
  __shared__ float cb_s[128];

  const int tid  = threadIdx.x;
  const int lane = tid & 63;
  const int l32  = lane & 31;
  const int l1   = lane >> 5;
  const int w    = tid >> 6;

  // XCD-locality remap: co-resident blocks (F, F+256) share b,h -> L1/L2 K reuse
  const int F    = blockIdx.x;
  const int xcd  = F & 7, rest = F >> 3;
  const int b    = xcd >> 2;
  const int h    = (xcd & 3) * 4 + (rest & 3);
  const int i0   = (rest >> 2) * 128;

  const float SC = 0.125f * 1.44269504088896f;
  for (int c = tid; c < DK_; c += 256) {
    union { _Float16 h; short s; } cv;
    cv.h = (_Float16)(mixing[(size_t)h * DK_ + c] * SC);
    mix_s[c] = cv.s;
  }

  const int iq = i0 + w * 32 + l32;
  const short* qptr  = Qf + ((size_t)b * S_ + iq) * DK_;
  const short* kbase = Kf + (size_t)b * S_ * DK_;
  const short* vtb   = Vtf + ((size_t)b * DV_ + h * DH_) * S_;
  const float* cbp   = CBs + ((size_t)b * H_ + h) * S_;

  float16v accS[4], accO[2];
  #pragma unroll
  for (int g = 0; g < 2; ++g)
    #pragma unroll
    for (int r = 0; r < 16; ++r) accO[g][r] = 0.f;
  float m_run = -1e30f, l_run = 0.f;

  // DMA geometry (per wave, 4 calls/chunk): call n = w*4+cc covers rows
  // 8n..8n+7 (8 rows x 128 B); lane l -> row 8n+(l>>3), phys16 p=l&7,
  // source logical chunk = p ^ (row&7) = (l&7) ^ (l>>3 & 7)
  const int dr   = lane >> 3;       // 0..7 (row within call)
  const int lch  = (lane & 7) ^ dr; // source 16B-chunk (swizzle)
  const int axor = l32 & 7;         // af read swizzle key

  const int vrow = tid >> 2;        // Vt stage: 64 rows, 4 thr/row
  const int vseg = (tid & 3) * 32;

  for (int j0 = 0; j0 < S_; j0 += 128) {
    // ---- stage V^T + cb ----
    short8 vreg[4];
    #pragma unroll
    for (int c = 0; c < 4; ++c)
      vreg[c] = *(const short8*)(vtb + (size_t)vrow * S_ + j0 + vseg + c * 8);
    float cbv = 0.f;
    if (tid < 128) cbv = cbp[j0 + tid];
    __syncthreads();   // [A] prev tile's Vt/cb consumers + last DMA done
    #pragma unroll
    for (int c = 0; c < 4; ++c)
      *(short8*)&Vt[vrow][vseg + c * 8] = vreg[c];
    if (tid < 128) cb_s[tid] = cbv;

    // ---- issue DMA chunk 0 + preload Q chunk 0 ----
    #pragma unroll
    for (int cc = 0; cc < 4; ++cc) {
      const int n = w * 4 + cc, row = 8 * n + dr;
      gll16(kbase + (size_t)(j0 + row) * DK_ + lch * 8, &Kbuf[0][n * 512]);
    }
    half8v qcur[4];
    #pragma unroll
    for (int ks = 0; ks < 4; ++ks)
      qcur[ks] = *(const half8v*)(qptr + ks * 16 + l1 * 8);

    #pragma unroll
    for (int f = 0; f < 4; ++f)
      #pragma unroll
      for (int r = 0; r < 16; ++r) accS[f][r] = 0.f;

    #pragma unroll 2
    for (int c = 0; c < 16; ++c) {
      __syncthreads();   // chunk c ready (DMA pre-elapsed), buf (c-1)&1 free
      if (c < 15) {
        const int cs = c + 1;
        #pragma unroll
        for (int cc = 0; cc < 4; ++cc) {
          const int n = w * 4 + cc, row = 8 * n + dr;
          gll16(kbase + (size_t)(j0 + row) * DK_ + cs * 64 + lch * 8,
                &Kbuf[cs & 1][n * 512]);
        }
      }
      half8v qnext[4];
      if (c < 15) {
        #pragma unroll
        for (int ks = 0; ks < 4; ++ks)
          qnext[ks] = *(const half8v*)(qptr + (c + 1) * 64 + ks * 16 + l1 * 8);
      }
      const short* kb = &Kbuf[c & 1][0];
      #pragma unroll
      for (int ks = 0; ks < 4; ++ks) {
        half8v mf = *(half8v*)&mix_s[c * 64 + ks * 16 + l1 * 8];
        half8v qm = qcur[ks] * mf;                 // v_pk_mul_f16
        #pragma unroll
        for (int f = 0; f < 4; ++f) {
          const int r = f * 32 + l32;
          half8v af = *(const half8v*)&kb[r * 64 + ((2 * ks + l1) ^ axor) * 8];
          accS[f] = __builtin_amdgcn_mfma_f32_32x32x16_f16(af, qm, accS[f], 0, 0, 0);
        }
      }
      if (c < 15) {
        #pragma unroll
        for (int ks = 0; ks < 4; ++ks) qcur[ks] = qnext[ks];
      }
    }

    // ---- online softmax: lane-local + 1 shfl ----
    float tmax = -1e30f;
    #pragma unroll
    for (int f = 0; f < 4; ++f)
      #pragma unroll
      for (int q = 0; q < 4; ++q) {
        float4 cbq = *(float4*)&cb_s[f * 32 + q * 8 + l1 * 4];
        #pragma unroll
        for (int c = 0; c < 4; ++c) {
          accS[f][4 * q + c] += ((const float*)&cbq)[c];
          tmax = fmaxf(tmax, accS[f][4 * q + c]);
        }
      }
    tmax = fmaxf(tmax, __shfl_xor(tmax, 32));
    const float mnew = fmaxf(m_run, tmax);
    const float alpha = exp2f(m_run - mnew);
    float tsum = 0.f;
    #pragma unroll
    for (int f = 0; f < 4; ++f)
      #pragma unroll
      for (int r = 0; r < 16; ++r) {
        float pv = exp2f(accS[f][r] - mnew);
        accS[f][r] = pv;
        tsum += pv;
      }
    tsum += __shfl_xor(tsum, 32);
    l_run = l_run * alpha + tsum;
    m_run = mnew;
    #pragma unroll
    for (int g = 0; g < 2; ++g)
      #pragma unroll
      for (int r = 0; r < 16; ++r) accO[g][r] *= alpha;

    // ---- PV: O^T[dv][i] += V^T[dv][j] @ P^T[j][i] ----
    #pragma unroll
    for (int cpv = 0; cpv < 8; ++cpv) {
      const int t = cpv & 1, fp = cpv >> 1;
      float xo[4], yo[4], lo[4], hi[4];
      #pragma unroll
      for (int c = 0; c < 4; ++c) {
        xo[c] = __shfl_xor(accS[fp][8 * t + c], 32);
        yo[c] = __shfl_xor(accS[fp][8 * t + 4 + c], 32);
      }
      #pragma unroll
      for (int c = 0; c < 4; ++c) {
        lo[c] = l1 ? yo[c] : accS[fp][8 * t + c];
        hi[c] = l1 ? accS[fp][8 * t + 4 + c] : xo[c];
      }
      union { half8v v; unsigned u[4]; } pb;
      pb.u[0] = pkrtz_u32(lo[0], lo[1]);
      pb.u[1] = pkrtz_u32(lo[2], lo[3]);
      pb.u[2] = pkrtz_u32(hi[0], hi[1]);
      pb.u[3] = pkrtz_u32(hi[2], hi[3]);
      #pragma unroll
      for (int g = 0; g < 2; ++g) {
        half8v vf = *(half8v*)&Vt[g * 32 + l32][cpv * 16 + l1 * 8];
        accO[g] = __builtin_amdgcn_mfma_f32_32x32x16_f16(vf, pb.v, accO[g], 0, 0, 0);
      }
    }
  }

  // ---- epilogue: normalize, store ctx (bf16) ----
  const float rl = 1.0f / l_run;
  short* cbase = ctxb + ((size_t)b * S_ + iq) * DV_ + h * DH_;
  #pragma unroll
  for (int g = 0; g < 2; ++g)
    #pragma unroll
    for (int q = 0; q < 4; ++q) {
      const int dv = g * 32 + 8 * q + 4 * l1;
      union { ushort4 u4; short s[4]; } ov;
      #pragma unroll
      for (int r = 0; r < 4; ++r)
        ov.s[r] = f_to_bf16s(accO[g][4 * q + r] * rl);
      *(ushort4*)(cbase + dv) = ov.u4;
    }
}

// ---------------- LayerNorm in-place on d_out ----------------
__global__ __launch_bounds__(256) void ln_kernel(float* __restrict__ out,
                                                 const float* __restrict__ gamma,
                                                 const float* __restrict__ beta) {
  __shared__ float red[8];
  const int row = blockIdx.x;
  const int tid = threadIdx.x;
  float* p = out + (size_t)row * DOUT_;
  float4 v = ((const float4*)p)[tid];
  float s = v.x + v.y + v.z + v.w;
  #pragma unroll
  for (int mk = 1; mk < 64; mk <<= 1) s += __shfl_xor(s, mk);
  if ((tid & 63) == 0) red[tid >> 6] = s;
  __syncthreads();
  const float mean = (red[0] + red[1] + red[2] + red[3]) * (1.0f / 1024.0f);
  const float d0 = v.x - mean, d1 = v.y - mean, d2 = v.z - mean, d3 = v.w - mean;
  float sq = d0 * d0 + d1 * d1 + d2 * d2 + d3 * d3;
  #pragma unroll
  for (int mk = 1; mk < 64; mk <<= 1) sq += __shfl_xor(sq, mk);
  if ((tid & 63) == 0) red[4 + (tid >> 6)] = sq;
  __syncthreads();
  const float var = (red[4] + red[5] + red[6] + red[7]) * (1.0f / 1024.0f);
  const float rstd = rsqrtf(var + 1e-5f);
  float4 g = ((const float4*)gamma)[tid];
  float4 bt = ((const float4*)beta)[tid];
  float4 o;
  o.x = d0 * rstd * g.x + bt.x;
  o.y = d1 * rstd * g.y + bt.y;
  o.z = d2 * rstd * g.z + bt.z;
  o.w = d3 * rstd * g.w + bt.w;
  ((float4*)p)[tid] = o;
}

extern "C" void kernel_launch(void* const* d_in, const int* in_sizes, int n_in,
                              void* d_out, int out_size, void* d_ws, size_t ws_size,
                              hipStream_t stream) {
  (void)in_sizes; (void)n_in; (void)out_size; (void)ws_size;
  const float* x      = (const float*)d_in[0];
  const float* Wq     = (const float*)d_in[1];
  const float* Wk     = (const float*)d_in[2];
  const float* Wcb    = (const float*)d_in[3];
  const float* Wv     = (const float*)d_in[4];
  const float* bv     = (const float*)d_in[5];
  const float* mixing = (const float*)d_in[6];
  const float* Wd     = (const float*)d_in[7];
  const float* bd     = (const float*)d_in[8];
  const float* gamma  = (const float*)d_in[9];
  const float* beta   = (const float*)d_in[10];
  float* out = (float*)d_out;

  short* p = (short*)d_ws;
  short* xb   = p; p += (size_t)M_ * DIN_;
  short* Qf   = p; p += (size_t)M_ * DK_;      // f16
  short* Kf   = p; p += (size_t)M_ * DK_;      // f16
  short* Vtf  = p; p += (size_t)B_ * DV_ * S_; // f16, [b][dv][s]
  short* ctxb = p; p += (size_t)M_ * DV_;      // bf16
  short* Wqb  = p; p += (size_t)DK_ * DIN_;
  short* Wkb  = p; p += (size_t)DK_ * DIN_;
  short* Wvb  = p; p += (size_t)DV_ * DIN_;
  short* Wdb  = p; p += (size_t)DOUT_ * DV_;
  float* CBs  = (float*)p;   // B*H*S floats

  cast_kernel<<<dim3(M_ * DIN_ / 1024), 256, 0, stream>>>(x, xb, M_ * DIN_ / 4);
  cast_kernel<<<dim3(DK_ * DIN_ / 1024), 256, 0, stream>>>(Wq, Wqb, DK_ * DIN_ / 4);
  cast_kernel<<<dim3(DK_ * DIN_ / 1024), 256, 0, stream>>>(Wk, Wkb, DK_ * DIN_ / 4);
  cast_kernel<<<dim3(DV_ * DIN_ / 1024), 256, 0, stream>>>(Wv, Wvb, DV_ * DIN_ / 4);
  cast_kernel<<<dim3(DOUT_ * DV_ / 1024), 256, 0, stream>>>(Wd, Wdb, DOUT_ * DV_ / 4);
  cb_kernel<<<dim3(M_), 256, 0, stream>>>(x, Wcb, CBs);

  gemm_qkv<<<dim3(48, M_ / 64), 256, 0, stream>>>(xb, Wqb, Wkb, Wvb, bv, Qf, Kf, Vtf);

  attn_kernel<<<dim3(512), 256, 0, stream>>>(Qf, Kf, Vtf, mixing, CBs, ctxb);

  gemm_out<<<dim3(16, M_ / 64), 256, 0, stream>>>(ctxb, Wdb, bd, x, out);
  ln_kernel<<<dim3(M_), 256, 0, stream>>>(out, gamma, beta);
}